// Round 2
// baseline (699.319 us; speedup 1.0000x reference)
//
#include <hip/hip_runtime.h>
#include <math.h>

#define NODES 50000
#define NEDGE 800000
#define ETOT  (NEDGE + NODES)

// ---- monotone float<->uint key for atomicMax on floats (incl. negatives) ----
__device__ __forceinline__ unsigned fkey(float f) {
    unsigned u = __float_as_uint(f);
    return (u & 0x80000000u) ? ~u : (u | 0x80000000u);
}
__device__ __forceinline__ float keyf(unsigned k) {
    unsigned u = (k & 0x80000000u) ? (k & 0x7FFFFFFFu) : ~k;
    return __uint_as_float(u);
}

// ---- GEMM: H[n,128] = X[n,128] @ W[128,128]; block=128 thr, ROWS rows/block ----
template<int ROWS>
__global__ void gemm_xw(const float* __restrict__ X, const float* __restrict__ W,
                        float* __restrict__ Hout, int n) {
    __shared__ float xs[ROWS][128];
    const int t = threadIdx.x;
    const int row0 = blockIdx.x * ROWS;
    #pragma unroll
    for (int r = 0; r < ROWS; ++r) {
        int row = row0 + r;
        xs[r][t] = (row < n) ? X[row * 128 + t] : 0.f;
    }
    __syncthreads();
    float acc[ROWS];
    #pragma unroll
    for (int r = 0; r < ROWS; ++r) acc[r] = 0.f;
    for (int k = 0; k < 128; ++k) {
        float w = W[k * 128 + t];
        #pragma unroll
        for (int r = 0; r < ROWS; ++r) acc[r] += xs[r][k] * w;  // LDS broadcast
    }
    #pragma unroll
    for (int r = 0; r < ROWS; ++r) {
        int row = row0 + r;
        if (row < n) Hout[row * 128 + t] = acc[r];
    }
}

// ---- GEMM2: H2[n,16] = Hin[n,128] @ W[128,16]; one thread per output elem ----
__global__ void gemm_hw2(const float* __restrict__ Hin, const float* __restrict__ W,
                         float* __restrict__ Hout, int n) {
    int tid = blockIdx.x * blockDim.x + threadIdx.x;
    int node = tid >> 4, col = tid & 15;
    if (node >= n) return;
    const float* hr = Hin + node * 128;
    float acc = 0.f;
    #pragma unroll
    for (int k = 0; k < 128; ++k) acc += hr[k] * W[k * 16 + col];
    Hout[node * 16 + col] = acc;
}

// ---- per-node alpha_src / alpha_dst dots: one wave per node ----
template<int F>
__global__ void alpha_kernel(const float* __restrict__ H, const float* __restrict__ a_src,
                             const float* __restrict__ a_dst,
                             float* __restrict__ as_, float* __restrict__ ad_, int n) {
    int wid = (blockIdx.x * blockDim.x + threadIdx.x) >> 6;
    int lane = threadIdx.x & 63;
    if (wid >= n) return;
    float s = 0.f, d = 0.f;
    for (int k = lane; k < F; k += 64) {
        float v = H[wid * F + k];
        s += v * a_src[k];
        d += v * a_dst[k];
    }
    #pragma unroll
    for (int off = 32; off; off >>= 1) {
        s += __shfl_down(s, off);
        d += __shfl_down(d, off);
    }
    if (lane == 0) { as_[wid] = s; ad_[wid] = d; }
}

// ---- edge pass 1: segment max (LeakyReLU'd scores) ----
__global__ void edge_max(const int* __restrict__ ei,
                         const float* __restrict__ as_, const float* __restrict__ ad_,
                         unsigned* __restrict__ mkey) {
    int e = blockIdx.x * blockDim.x + threadIdx.x;
    if (e >= ETOT) return;
    int s, d;
    if (e < NEDGE) { s = ei[e]; d = ei[NEDGE + e]; }
    else           { s = d = e - NEDGE; }
    float v = as_[s] + ad_[d];
    v = (v >= 0.f) ? v : 0.2f * v;
    atomicMax(&mkey[d], fkey(v));
}

// ---- edge pass 2: exp and segment sum ----
__global__ void edge_expsum(const int* __restrict__ ei,
                            const float* __restrict__ as_, const float* __restrict__ ad_,
                            const unsigned* __restrict__ mkey,
                            float* __restrict__ ex, float* __restrict__ denom) {
    int e = blockIdx.x * blockDim.x + threadIdx.x;
    if (e >= ETOT) return;
    int s, d;
    if (e < NEDGE) { s = ei[e]; d = ei[NEDGE + e]; }
    else           { s = d = e - NEDGE; }
    float v = as_[s] + ad_[d];
    v = (v >= 0.f) ? v : 0.2f * v;
    float x = expf(v - keyf(mkey[d]));
    ex[e] = x;
    atomicAdd(&denom[d], x);
}

// ---- edge pass 3: weighted scatter-add of source features ----
template<int F, int SH>
__global__ void edge_aggregate(const int* __restrict__ ei,
                               const float* __restrict__ H, const float* __restrict__ ex,
                               const float* __restrict__ denom, float* __restrict__ out) {
    int tid = blockIdx.x * blockDim.x + threadIdx.x;
    int e = tid >> SH;
    int k = tid & (F - 1);
    if (e >= ETOT) return;
    int s, d;
    if (e < NEDGE) { s = ei[e]; d = ei[NEDGE + e]; }
    else           { s = d = e - NEDGE; }
    float w = ex[e] / (denom[d] + 1e-16f);
    atomicAdd(&out[d * F + k], w * H[s * F + k]);
}

// ---- bias + relu (in place) ----
__global__ void bias_relu(float* __restrict__ A, const float* __restrict__ b, int n) {
    int i = blockIdx.x * blockDim.x + threadIdx.x;
    if (i >= n) return;
    float v = A[i] + b[i & 127];
    A[i] = v > 0.f ? v : 0.f;
}

// ---- bias + log_softmax over 16 classes ----
__global__ void bias_logsoftmax(const float* __restrict__ A, const float* __restrict__ b,
                                float* __restrict__ out, int n) {
    int node = blockIdx.x * blockDim.x + threadIdx.x;
    if (node >= n) return;
    float v[16];
    float m = -INFINITY;
    #pragma unroll
    for (int k = 0; k < 16; ++k) { v[k] = A[node * 16 + k] + b[k]; m = fmaxf(m, v[k]); }
    float ssum = 0.f;
    #pragma unroll
    for (int k = 0; k < 16; ++k) ssum += expf(v[k] - m);
    float ls = logf(ssum);
    #pragma unroll
    for (int k = 0; k < 16; ++k) out[node * 16 + k] = v[k] - m - ls;
}

extern "C" void kernel_launch(void* const* d_in, const int* in_sizes, int n_in,
                              void* d_out, int out_size, void* d_ws, size_t ws_size,
                              hipStream_t stream) {
    const float* x      = (const float*)d_in[0];
    const int*   ei     = (const int*)d_in[1];   // [2, E] pushed as int32 by harness
    const float* W1     = (const float*)d_in[2];
    const float* a_src1 = (const float*)d_in[3];
    const float* a_dst1 = (const float*)d_in[4];
    const float* b1     = (const float*)d_in[5];
    const float* W2     = (const float*)d_in[6];
    const float* a_src2 = (const float*)d_in[7];
    const float* a_dst2 = (const float*)d_in[8];
    const float* b2     = (const float*)d_in[9];
    float* out = (float*)d_out;

    // workspace layout (fp32 elements)
    float* p = (float*)d_ws;
    float* h1   = p; p += (size_t)NODES * 128;
    float* agg1 = p; p += (size_t)NODES * 128;
    float* h2   = p; p += (size_t)NODES * 16;
    float* agg2 = p; p += (size_t)NODES * 16;
    float* as_  = p; p += NODES;
    float* ad_  = p; p += NODES;
    unsigned* mkey = (unsigned*)p; p += NODES;
    float* denom = p; p += NODES;
    float* ex    = p; p += ETOT;

    const int EB = (ETOT + 255) / 256;

    // ---------- layer 1 ----------
    gemm_xw<8><<<(NODES + 7) / 8, 128, 0, stream>>>(x, W1, h1, NODES);
    alpha_kernel<128><<<(NODES * 64 + 255) / 256, 256, 0, stream>>>(h1, a_src1, a_dst1, as_, ad_, NODES);
    hipMemsetAsync(mkey, 0, NODES * sizeof(unsigned), stream);   // key 0 == -inf sentinel
    hipMemsetAsync(denom, 0, NODES * sizeof(float), stream);
    edge_max<<<EB, 256, 0, stream>>>(ei, as_, ad_, mkey);
    edge_expsum<<<EB, 256, 0, stream>>>(ei, as_, ad_, mkey, ex, denom);
    hipMemsetAsync(agg1, 0, (size_t)NODES * 128 * sizeof(float), stream);
    edge_aggregate<128, 7><<<(unsigned)(((size_t)ETOT * 128 + 255) / 256), 256, 0, stream>>>(ei, h1, ex, denom, agg1);
    bias_relu<<<(NODES * 128 + 255) / 256, 256, 0, stream>>>(agg1, b1, NODES * 128);

    // ---------- layer 2 ----------
    gemm_hw2<<<(NODES * 16 + 255) / 256, 256, 0, stream>>>(agg1, W2, h2, NODES);
    alpha_kernel<16><<<(NODES * 64 + 255) / 256, 256, 0, stream>>>(h2, a_src2, a_dst2, as_, ad_, NODES);
    hipMemsetAsync(mkey, 0, NODES * sizeof(unsigned), stream);
    hipMemsetAsync(denom, 0, NODES * sizeof(float), stream);
    edge_max<<<EB, 256, 0, stream>>>(ei, as_, ad_, mkey);
    edge_expsum<<<EB, 256, 0, stream>>>(ei, as_, ad_, mkey, ex, denom);
    hipMemsetAsync(agg2, 0, (size_t)NODES * 16 * sizeof(float), stream);
    edge_aggregate<16, 4><<<(unsigned)(((size_t)ETOT * 16 + 255) / 256), 256, 0, stream>>>(ei, h2, ex, denom, agg2);
    bias_logsoftmax<<<(NODES + 255) / 256, 256, 0, stream>>>(agg2, b2, out, NODES);
}

// Round 3
// 289.329 us; speedup vs baseline: 2.4170x; 2.4170x over previous
//
#include <hip/hip_runtime.h>
#include <math.h>

#define NODES 50000
#define NEDGE 800000
#define ETOT  (NEDGE + NODES)
#define NEGF  -1e30f   // finite -inf sentinel: avoids (-inf) - (-inf) = NaN in combines

// ---- GEMM: H[n,128] = X[n,128] @ W[128,128]; block=128 thr, ROWS rows/block ----
template<int ROWS>
__global__ void gemm_xw(const float* __restrict__ X, const float* __restrict__ W,
                        float* __restrict__ Hout, int n) {
    __shared__ float xs[ROWS][128];
    const int t = threadIdx.x;
    const int row0 = blockIdx.x * ROWS;
    #pragma unroll
    for (int r = 0; r < ROWS; ++r) {
        int row = row0 + r;
        xs[r][t] = (row < n) ? X[row * 128 + t] : 0.f;
    }
    __syncthreads();
    float acc[ROWS];
    #pragma unroll
    for (int r = 0; r < ROWS; ++r) acc[r] = 0.f;
    for (int k = 0; k < 128; ++k) {
        float w = W[k * 128 + t];
        #pragma unroll
        for (int r = 0; r < ROWS; ++r) acc[r] += xs[r][k] * w;  // LDS broadcast
    }
    #pragma unroll
    for (int r = 0; r < ROWS; ++r) {
        int row = row0 + r;
        if (row < n) Hout[row * 128 + t] = acc[r];
    }
}

// ---- GEMM2: H2[n,16] = Hin[n,128] @ W[128,16] ----
__global__ void gemm_hw2(const float* __restrict__ Hin, const float* __restrict__ W,
                         float* __restrict__ Hout, int n) {
    int tid = blockIdx.x * blockDim.x + threadIdx.x;
    int node = tid >> 4, col = tid & 15;
    if (node >= n) return;
    const float* hr = Hin + (size_t)node * 128;
    float acc = 0.f;
    #pragma unroll
    for (int k = 0; k < 128; ++k) acc += hr[k] * W[k * 16 + col];
    Hout[(size_t)node * 16 + col] = acc;
}

// ---- per-node alpha_src / alpha_dst dots: one wave per node ----
template<int F>
__global__ void alpha_kernel(const float* __restrict__ H, const float* __restrict__ a_src,
                             const float* __restrict__ a_dst,
                             float* __restrict__ as_, float* __restrict__ ad_, int n) {
    int wid = (blockIdx.x * blockDim.x + threadIdx.x) >> 6;
    int lane = threadIdx.x & 63;
    if (wid >= n) return;
    float s = 0.f, d = 0.f;
    for (int k = lane; k < F; k += 64) {
        float v = H[(size_t)wid * F + k];
        s += v * a_src[k];
        d += v * a_dst[k];
    }
    #pragma unroll
    for (int off = 32; off; off >>= 1) {
        s += __shfl_down(s, off);
        d += __shfl_down(d, off);
    }
    if (lane == 0) { as_[wid] = s; ad_[wid] = d; }
}

// =================== CSR build (once per call, shared by both layers) =========
__global__ void csr_hist(const int* __restrict__ ei, int* __restrict__ deg) {
    int e = blockIdx.x * blockDim.x + threadIdx.x;
    if (e >= ETOT) return;
    int d = (e < NEDGE) ? ei[NEDGE + e] : e - NEDGE;
    atomicAdd(&deg[d], 1);
}

// per-256-chunk sums
__global__ void scan1(const int* __restrict__ deg, int* __restrict__ bsum) {
    int i = blockIdx.x * 256 + threadIdx.x;
    int v = (i < NODES) ? deg[i] : 0;
    #pragma unroll
    for (int off = 32; off; off >>= 1) v += __shfl_down(v, off);
    __shared__ int ws[4];
    if ((threadIdx.x & 63) == 0) ws[threadIdx.x >> 6] = v;
    __syncthreads();
    if (threadIdx.x == 0) bsum[blockIdx.x] = ws[0] + ws[1] + ws[2] + ws[3];
}

// single-block exclusive scan of nb (<=256) block sums
__global__ void scan2(int* __restrict__ bsum, int nb) {
    int t = threadIdx.x;
    int lane = t & 63, w = t >> 6;
    int v = (t < nb) ? bsum[t] : 0;
    int sv = v;
    #pragma unroll
    for (int off = 1; off < 64; off <<= 1) {
        int o = __shfl_up(sv, off);
        if (lane >= off) sv += o;
    }
    __shared__ int wsum[4];
    if (lane == 63) wsum[w] = sv;
    __syncthreads();
    int add = 0;
    for (int j = 0; j < w; ++j) add += wsum[j];
    sv += add;
    if (t < nb) bsum[t] = sv - v;   // exclusive
}

// per-chunk scan + global offset -> rowptr, cursor
__global__ void scan3(const int* __restrict__ deg, const int* __restrict__ bsum,
                      int* __restrict__ rowptr, int* __restrict__ cursor) {
    int i = blockIdx.x * 256 + threadIdx.x;
    int v = (i < NODES) ? deg[i] : 0;
    int lane = threadIdx.x & 63, w = threadIdx.x >> 6;
    int sv = v;
    #pragma unroll
    for (int off = 1; off < 64; off <<= 1) {
        int o = __shfl_up(sv, off);
        if (lane >= off) sv += o;
    }
    __shared__ int wsum[4];
    if (lane == 63) wsum[w] = sv;
    __syncthreads();
    int add = bsum[blockIdx.x];
    for (int j = 0; j < w; ++j) add += wsum[j];
    int excl = add + sv - v;
    if (i < NODES) { rowptr[i] = excl; cursor[i] = excl; }
    if (i == NODES - 1) rowptr[NODES] = excl + v;
}

__global__ void csr_fill(const int* __restrict__ ei, int* __restrict__ cursor,
                         int* __restrict__ srcs) {
    int e = blockIdx.x * blockDim.x + threadIdx.x;
    if (e >= ETOT) return;
    int s, d;
    if (e < NEDGE) { s = ei[e]; d = ei[NEDGE + e]; }
    else           { s = d = e - NEDGE; }
    int pos = atomicAdd(&cursor[d], 1);
    srcs[pos] = s;
}

// ======= layer 1: per-node online-softmax aggregate + bias + ReLU (F=128) =====
// one wave per node; lane covers features {2*lane, 2*lane+1}; 2-edge unroll for MLP
__global__ void gat_aggregate128(const int* __restrict__ rowptr, const int* __restrict__ srcs,
                                 const float* __restrict__ H, const float* __restrict__ as_,
                                 const float* __restrict__ ad_, const float* __restrict__ b,
                                 float* __restrict__ out) {
    int wid = (blockIdx.x * blockDim.x + threadIdx.x) >> 6;
    int lane = threadIdx.x & 63;
    if (wid >= NODES) return;
    const int beg = rowptr[wid], end = rowptr[wid + 1];
    const float adv = ad_[wid];
    float m = NEGF, den = 0.f;
    float ax = 0.f, ay = 0.f;
    int i = beg;
    for (; i + 1 < end; i += 2) {
        int s0 = srcs[i], s1 = srcs[i + 1];
        float v0 = as_[s0] + adv; v0 = (v0 >= 0.f) ? v0 : 0.2f * v0;
        float v1 = as_[s1] + adv; v1 = (v1 >= 0.f) ? v1 : 0.2f * v1;
        const float2 h0 = *(const float2*)(H + (size_t)s0 * 128 + lane * 2);
        const float2 h1 = *(const float2*)(H + (size_t)s1 * 128 + lane * 2);
        float mn = fmaxf(m, fmaxf(v0, v1));
        float scale = __expf(m - mn);
        float w0 = __expf(v0 - mn), w1 = __expf(v1 - mn);
        den = den * scale + w0 + w1;
        ax = ax * scale + w0 * h0.x + w1 * h1.x;
        ay = ay * scale + w0 * h0.y + w1 * h1.y;
        m = mn;
    }
    if (i < end) {
        int s0 = srcs[i];
        float v0 = as_[s0] + adv; v0 = (v0 >= 0.f) ? v0 : 0.2f * v0;
        const float2 h0 = *(const float2*)(H + (size_t)s0 * 128 + lane * 2);
        float mn = fmaxf(m, v0);
        float scale = __expf(m - mn);
        float w0 = __expf(v0 - mn);
        den = den * scale + w0;
        ax = ax * scale + w0 * h0.x;
        ay = ay * scale + w0 * h0.y;
        m = mn;
    }
    float inv = 1.f / (den + 1e-16f);
    float2 o;
    o.x = fmaxf(ax * inv + b[lane * 2], 0.f);
    o.y = fmaxf(ay * inv + b[lane * 2 + 1], 0.f);
    *(float2*)(out + (size_t)wid * 128 + lane * 2) = o;
}

// == layer 2: per-node aggregate (F=16, 4 edge-slots/wave) + bias + log_softmax ==
__global__ void gat_aggregate16_lsm(const int* __restrict__ rowptr, const int* __restrict__ srcs,
                                    const float* __restrict__ H, const float* __restrict__ as_,
                                    const float* __restrict__ ad_, const float* __restrict__ b,
                                    float* __restrict__ out) {
    int wid = (blockIdx.x * blockDim.x + threadIdx.x) >> 6;
    int lane = threadIdx.x & 63;
    int slot = lane >> 4, k = lane & 15;
    if (wid >= NODES) return;
    const int beg = rowptr[wid], end = rowptr[wid + 1];
    const float adv = ad_[wid];
    float m = NEGF, den = 0.f, acc = 0.f;
    for (int i = beg + slot; i < end; i += 4) {
        int s = srcs[i];
        float v = as_[s] + adv; v = (v >= 0.f) ? v : 0.2f * v;
        float mn = fmaxf(m, v);
        float scale = __expf(m - mn);
        float w = __expf(v - mn);
        den = den * scale + w;
        acc = acc * scale + w * H[(size_t)s * 16 + k];
        m = mn;
    }
    // combine the 4 slots (butterfly; lanes with same k pair up at offsets 16,32)
    #pragma unroll
    for (int off = 16; off < 64; off <<= 1) {
        float mo = __shfl_xor(m, off);
        float deno = __shfl_xor(den, off);
        float acco = __shfl_xor(acc, off);
        float mn = fmaxf(m, mo);
        float sa = __expf(m - mn), sb = __expf(mo - mn);
        den = den * sa + deno * sb;
        acc = acc * sa + acco * sb;
        m = mn;
    }
    float v = acc / (den + 1e-16f) + b[k];
    // log_softmax across the 16 features (within each 16-lane group)
    float mx = v;
    #pragma unroll
    for (int off = 1; off < 16; off <<= 1) mx = fmaxf(mx, __shfl_xor(mx, off));
    float ex = __expf(v - mx), ssum = ex;
    #pragma unroll
    for (int off = 1; off < 16; off <<= 1) ssum += __shfl_xor(ssum, off);
    float r = v - mx - __logf(ssum);
    if (lane < 16) out[(size_t)wid * 16 + k] = r;
}

extern "C" void kernel_launch(void* const* d_in, const int* in_sizes, int n_in,
                              void* d_out, int out_size, void* d_ws, size_t ws_size,
                              hipStream_t stream) {
    const float* x      = (const float*)d_in[0];
    const int*   ei     = (const int*)d_in[1];   // [2, E] int32 on device
    const float* W1     = (const float*)d_in[2];
    const float* a_src1 = (const float*)d_in[3];
    const float* a_dst1 = (const float*)d_in[4];
    const float* b1     = (const float*)d_in[5];
    const float* W2     = (const float*)d_in[6];
    const float* a_src2 = (const float*)d_in[7];
    const float* a_dst2 = (const float*)d_in[8];
    const float* b2     = (const float*)d_in[9];
    float* out = (float*)d_out;

    // ---- workspace layout ----
    float* p = (float*)d_ws;
    float* h1   = p; p += (size_t)NODES * 128;   // 25.6 MB
    float* agg1 = p; p += (size_t)NODES * 128;   // 25.6 MB
    float* h2   = p; p += (size_t)NODES * 16;    //  3.2 MB
    float* as_  = p; p += NODES;
    float* ad_  = p; p += NODES;
    int* ip = (int*)p;
    int* deg    = ip; ip += NODES;
    int* cursor = ip; ip += NODES;
    int* rowptr = ip; ip += NODES + 1;
    int* srcs   = ip; ip += ETOT;
    int* bsum   = ip; ip += 256;

    const int EB = (ETOT + 255) / 256;
    const int NB = (NODES + 255) / 256;   // 196 chunks

    // ---- CSR build (shared by both layers) ----
    hipMemsetAsync(deg, 0, NODES * sizeof(int), stream);
    csr_hist<<<EB, 256, 0, stream>>>(ei, deg);
    scan1<<<NB, 256, 0, stream>>>(deg, bsum);
    scan2<<<1, 256, 0, stream>>>(bsum, NB);
    scan3<<<NB, 256, 0, stream>>>(deg, bsum, rowptr, cursor);
    csr_fill<<<EB, 256, 0, stream>>>(ei, cursor, srcs);

    // ---- layer 1 ----
    gemm_xw<8><<<(NODES + 7) / 8, 128, 0, stream>>>(x, W1, h1, NODES);
    alpha_kernel<128><<<(NODES * 64 + 255) / 256, 256, 0, stream>>>(h1, a_src1, a_dst1, as_, ad_, NODES);
    gat_aggregate128<<<(NODES * 64 + 255) / 256, 256, 0, stream>>>(rowptr, srcs, h1, as_, ad_, b1, agg1);

    // ---- layer 2 ----
    gemm_hw2<<<(NODES * 16 + 255) / 256, 256, 0, stream>>>(agg1, W2, h2, NODES);
    alpha_kernel<16><<<(NODES * 64 + 255) / 256, 256, 0, stream>>>(h2, a_src2, a_dst2, as_, ad_, NODES);
    gat_aggregate16_lsm<<<(NODES * 64 + 255) / 256, 256, 0, stream>>>(rowptr, srcs, h2, as_, ad_, b2, out);
}